// Round 3
// baseline (387.886 us; speedup 1.0000x reference)
//
#include <hip/hip_runtime.h>

typedef __attribute__((ext_vector_type(8))) short bf16x8;
typedef __attribute__((ext_vector_type(4))) short bf16x4;
typedef __attribute__((ext_vector_type(4))) float f32x4;

#define OUT0 524288           // B*G*E
#define SRC_CH_STRIDE 8388608 // B*G*G = 2*2048*2048
#define PART_HEAD 544         // m[16] + l[16] + O[16*32]
#define PART_SLICE 2176       // 4 heads * 544
#define NSLICE 8

__device__ __forceinline__ unsigned short f2bf(float x){
    unsigned u = __builtin_bit_cast(unsigned, x);
    u += 0x7FFFu + ((u >> 16) & 1u);
    return (unsigned short)(u >> 16);
}

__device__ __forceinline__ f32x4 mfma16x16x16_bf16(bf16x4 a, bf16x4 b, f32x4 c){
#if __has_builtin(__builtin_amdgcn_mfma_f32_16x16x16bf16_1k)
    return __builtin_amdgcn_mfma_f32_16x16x16bf16_1k(a, b, c, 0, 0, 0);
#else
    f32x4 d;
    asm volatile("v_mfma_f32_16x16x16_bf16 %0, %1, %2, %3"
                 : "=v"(d) : "v"(a), "v"(b), "v"(c));
    return d;
#endif
}

// ---------------- kernel 1: QKV projection ----------------
// grid (128 row-tiles of 32, 12 = 3 mats x 4 heads), block 256
// Q,K -> bf16 [b][g][head*32+k] ; V -> bf16 transposed [b][head*32+v][g]
__global__ __launch_bounds__(256) void qkv_kernel(
    const float* __restrict__ hsrc,
    const float* __restrict__ Wq, const float* __restrict__ Wk, const float* __restrict__ Wv,
    unsigned short* __restrict__ Qb, unsigned short* __restrict__ Kb, unsigned short* __restrict__ Vt)
{
    __shared__ float hs[32*128];
    __shared__ float ws[128*32];
    const int t = threadIdx.x;
    const int g0 = blockIdx.x * 32;
    const int mat = blockIdx.y;
    const int mt = mat >> 2, head = mat & 3;
    {
        const float4* s = (const float4*)(hsrc + g0*128);
        float4* d = (float4*)hs;
        #pragma unroll
        for (int i=0;i<4;i++) d[t + i*256] = s[t + i*256];
        const float* W = (mt==0?Wq:(mt==1?Wk:Wv)) + head*4096;
        const float4* s2 = (const float4*)W;
        float4* d2 = (float4*)ws;
        #pragma unroll
        for (int i=0;i<4;i++) d2[t + i*256] = s2[t + i*256];
    }
    __syncthreads();
    const int r = t >> 3;          // 0..31 row in tile
    const int k0 = (t & 7) * 4;    // 0..28 out col group
    float a0=0.f,a1=0.f,a2=0.f,a3=0.f;
    const float* hr = hs + r*128;
    #pragma unroll 8
    for (int d=0; d<128; d++){
        float hv = hr[d];
        float4 w4 = *(const float4*)(ws + d*32 + k0);
        a0 = fmaf(hv, w4.x, a0); a1 = fmaf(hv, w4.y, a1);
        a2 = fmaf(hv, w4.z, a2); a3 = fmaf(hv, w4.w, a3);
    }
    const int row_g = g0 + r;
    if (mt == 2){
        const int b = row_g >> 11, g = row_g & 2047;
        unsigned short* dst = Vt + ((b*128 + head*32 + k0) * 2048) + g;
        dst[0] = f2bf(a0); dst[2048] = f2bf(a1); dst[4096] = f2bf(a2); dst[6144] = f2bf(a3);
    } else {
        unsigned short* dst = (mt==0?Qb:Kb) + row_g*128 + head*32 + k0;
        dst[0]=f2bf(a0); dst[1]=f2bf(a1); dst[2]=f2bf(a2); dst[3]=f2bf(a3);
    }
}

// ---------------- kernel 2: fused attention, wave-local, ZERO barriers in loop ----------------
// grid (32 q-chunks, B=2, NSLICE p-slices), block 256 = 4 waves.
// Each wave independently owns one 16-row q-tile x ALL 4 heads x its p-slice.
// Swapped QK^T: mfma(A=K, B=Q) -> lane holds S[h][p=quad*4+r][q=lrow] for all h
// in-lane -> MLP is lane-local (no LDS), softmax over p = 2 shfl_xor, and
// P[p=quad*4+r][q=lrow] is exactly the B-operand of mfma_16x16x16_bf16 with
// V^T rows as the A-operand. Only LDS use: 112-float broadcast weight table.
__global__ __launch_bounds__(256, 2) void attn_kernel(
    const float* __restrict__ src,
    const unsigned short* __restrict__ Qb,
    const unsigned short* __restrict__ Kb,
    const unsigned short* __restrict__ Vt,
    const float* __restrict__ w1g, const float* __restrict__ b1g,
    const float* __restrict__ w2g, const float* __restrict__ b2g,
    float* __restrict__ part,
    float* __restrict__ out)
{
    // wt: w1 rows [0..63], b1 [64..71], w2T [72+j*4+cc] = w2[cc][j], b2 [104..107]
    __shared__ __align__(16) float wt[112];

    const int t = threadIdx.x;
    const int lane = t & 63;
    const int wv = t >> 6;
    const int quad = lane >> 4;
    const int lrow = lane & 15;
    const int qt = blockIdx.x * 4 + wv;     // q-tile 0..127
    const int q0 = qt * 16;
    const int b = blockIdx.y;
    const int s = blockIdx.z;
    const int pbase = s * (2048 / NSLICE);  // 256 p per slice

    if (t < 64) wt[t] = w1g[t];
    else if (t < 72) wt[t] = b1g[t-64];
    else if (t < 104){ const int j = (t-72) >> 2, cc = (t-72) & 3; wt[t] = w2g[cc*8 + j]; }
    else if (t < 108) wt[t] = b2g[t-104];

    // Q fragments (B-operand of swapped QK^T): B[q=lrow][k=quad*8+j], all 4 heads
    bf16x8 qf[4];
    {
        const unsigned short* Qrow = Qb + (b*2048 + q0 + lrow)*128 + quad*8;
        #pragma unroll
        for (int h=0; h<4; h++) qf[h] = *(const bf16x8*)(Qrow + h*32);
    }

    const int rowbase = (b*2048 + q0 + lrow)*2048;   // src row for q=lrow
    const long vbase  = (long)(b*128)*2048;          // Vt batch base

    f32x4 o[4][2];                 // o[h][half]: O^T[v=half*16+quad*4+reg][q=lrow]
    float mreg[4], lreg[4];
    #pragma unroll
    for (int h=0; h<4; h++){
        o[h][0] = (f32x4){0.f,0.f,0.f,0.f};
        o[h][1] = (f32x4){0.f,0.f,0.f,0.f};
        mreg[h] = -1e30f; lreg[h] = 0.f;
    }
    const f32x4 zero4 = {0.f,0.f,0.f,0.f};

    __syncthreads();   // weight table ready; the ONLY barrier in this kernel

    for (int it = 0; it < (2048/NSLICE)/16; ++it){
        const int p0 = pbase + it*16;

        // ---- src loads (longest latency: issue first) ----
        float xr[4][4];
        {
            float4 r4[4];
            #pragma unroll
            for (int ch=0; ch<4; ch++)
                r4[ch] = *(const float4*)(src + ch*SRC_CH_STRIDE + rowbase + p0 + quad*4);
            // write-through (fire-and-forget; no barrier ever waits on these)
            #pragma unroll
            for (int ch=0; ch<4; ch++)
                *(float4*)(out + OUT0 + ch*SRC_CH_STRIDE + rowbase + p0 + quad*4) = r4[ch];
            #pragma unroll
            for (int ch=0; ch<4; ch++){
                xr[ch][0]=r4[ch].x; xr[ch][1]=r4[ch].y; xr[ch][2]=r4[ch].z; xr[ch][3]=r4[ch].w;
            }
        }

        // ---- V fragments for PV (A-operand): Vt[v=lrow][p=p0+quad*4+j] ----
        bf16x4 vf[4][2];
        #pragma unroll
        for (int h=0; h<4; h++){
            #pragma unroll
            for (int half=0; half<2; half++)
                vf[h][half] = *(const bf16x4*)(Vt + vbase + (long)(h*32 + half*16 + lrow)*2048 + p0 + quad*4);
        }

        // ---- swapped QK^T: lane gets S[h][p=quad*4+r][q=lrow], all heads in-lane ----
        f32x4 sc[4];
        {
            const unsigned short* Krow = Kb + (b*2048 + p0 + lrow)*128 + quad*8;
            #pragma unroll
            for (int h=0; h<4; h++){
                const bf16x8 kf = *(const bf16x8*)(Krow + h*32);
                sc[h] = __builtin_amdgcn_mfma_f32_16x16x32_bf16(kf, qf[h], zero4, 0, 0, 0);
            }
        }

        // ---- lane-local MLP: 4 cells (q=lrow, p=quad*4+r), 8ch -> relu8 -> 4 ----
        float z[4][4];
        #pragma unroll
        for (int cc=0; cc<4; cc++){
            const float bb = wt[104+cc];
            #pragma unroll
            for (int r=0; r<4; r++) z[cc][r] = bb;
        }
        #pragma unroll
        for (int j=0; j<8; j++){
            const float4 wa  = *(const float4*)(wt + j*8);
            const float4 wb  = *(const float4*)(wt + j*8 + 4);
            const float  bj  = wt[64+j];
            const float4 w2r = *(const float4*)(wt + 72 + j*4);
            #pragma unroll
            for (int r=0; r<4; r++){
                float v = bj;
                v = fmaf(wa.x, sc[0][r], v);
                v = fmaf(wa.y, sc[1][r], v);
                v = fmaf(wa.z, sc[2][r], v);
                v = fmaf(wa.w, sc[3][r], v);
                v = fmaf(wb.x, xr[0][r], v);
                v = fmaf(wb.y, xr[1][r], v);
                v = fmaf(wb.z, xr[2][r], v);
                v = fmaf(wb.w, xr[3][r], v);
                v = fmaxf(v, 0.f);
                z[0][r] = fmaf(w2r.x, v, z[0][r]);
                z[1][r] = fmaf(w2r.y, v, z[1][r]);
                z[2][r] = fmaf(w2r.z, v, z[2][r]);
                z[3][r] = fmaf(w2r.w, v, z[3][r]);
            }
        }

        // ---- online softmax (per head, over p) + PV via 16x16x16 MFMA ----
        #pragma unroll
        for (int h=0; h<4; h++){
            float mloc = fmaxf(fmaxf(z[h][0], z[h][1]), fmaxf(z[h][2], z[h][3]));
            mloc = fmaxf(mloc, __shfl_xor(mloc, 16));
            mloc = fmaxf(mloc, __shfl_xor(mloc, 32));
            const float mn = fmaxf(mreg[h], mloc);
            const float e0 = __expf(z[h][0] - mn);
            const float e1 = __expf(z[h][1] - mn);
            const float e2 = __expf(z[h][2] - mn);
            const float e3 = __expf(z[h][3] - mn);
            float ss = (e0 + e1) + (e2 + e3);
            ss += __shfl_xor(ss, 16);
            ss += __shfl_xor(ss, 32);
            const float alpha = __expf(mreg[h] - mn);
            mreg[h] = mn;
            lreg[h] = fmaf(lreg[h], alpha, ss);
            o[h][0] *= alpha;
            o[h][1] *= alpha;
            bf16x4 pf;
            pf[0] = (short)f2bf(e0); pf[1] = (short)f2bf(e1);
            pf[2] = (short)f2bf(e2); pf[3] = (short)f2bf(e3);
            o[h][0] = mfma16x16x16_bf16(vf[h][0], pf, o[h][0]);
            o[h][1] = mfma16x16x16_bf16(vf[h][1], pf, o[h][1]);
        }
    }

    // ---- write per-head partials: m[16], l[16], O[16][32] (un-normalized) ----
    #pragma unroll
    for (int h=0; h<4; h++){
        float* P = part + (((b*128 + qt)*NSLICE + s)*4 + h) * PART_HEAD;
        if (quad == 0){
            P[lrow]      = mreg[h];
            P[16 + lrow] = lreg[h];
        }
        *(f32x4*)(P + 32 + lrow*32 +      quad*4) = o[h][0];
        *(f32x4*)(P + 32 + lrow*32 + 16 + quad*4) = o[h][1];
    }
}

// ---------------- kernel 3: slice combine + output projection ----------------
// grid (128, 2), block 256
__global__ __launch_bounds__(256) void combine_kernel(
    const float* __restrict__ part,
    const float* __restrict__ Wout,
    float* __restrict__ out)
{
    __shared__ __align__(16) float O_lds[64*33];
    const int t = threadIdx.x;
    const int qt = blockIdx.x, b = blockIdx.y;

    if (t < 64){
        const int c = t >> 4, q = t & 15;
        const float* P0 = part + (((b*128 + qt)*NSLICE + 0)*4 + c) * PART_HEAD;
        float m[NSLICE];
        #pragma unroll
        for (int j=0;j<NSLICE;j++) m[j] = P0[j*PART_SLICE + q];
        float M = m[0];
        #pragma unroll
        for (int j=1;j<NSLICE;j++) M = fmaxf(M, m[j]);
        float w[NSLICE];
        float L = 0.f;
        #pragma unroll
        for (int j=0;j<NSLICE;j++){
            w[j] = __expf(m[j] - M);
            L = fmaf(P0[j*PART_SLICE + 16 + q], w[j], L);
        }
        float invL = 1.f / L;
        const float* O0 = P0 + 32 + q*32;
        float* dst = O_lds + t*33;
        #pragma unroll
        for (int v4 = 0; v4 < 8; v4++){
            float ax=0.f, ay=0.f, az=0.f, aw=0.f;
            #pragma unroll
            for (int j=0;j<NSLICE;j++){
                float4 a = *(const float4*)(O0 + j*PART_SLICE + v4*4);
                ax = fmaf(a.x, w[j], ax);
                ay = fmaf(a.y, w[j], ay);
                az = fmaf(a.z, w[j], az);
                aw = fmaf(a.w, w[j], aw);
            }
            dst[v4*4+0] = ax * invL;
            dst[v4*4+1] = ay * invL;
            dst[v4*4+2] = az * invL;
            dst[v4*4+3] = aw * invL;
        }
    }
    __syncthreads();

    // projection: out[b, q0+mq, :] = sum_c O[c, mq, :] @ Wout[c]
    {
        const int mq = t >> 4;
        const int e0 = (t & 15) * 8;
        float acc[8];
        #pragma unroll
        for (int i=0;i<8;i++) acc[i]=0.f;
        #pragma unroll
        for (int cc=0; cc<4; cc++){
            const float* OhRow = O_lds + (cc*16 + mq)*33;
            const float* Wrow = Wout + cc*32*128 + e0;
            #pragma unroll 4
            for (int v=0; v<32; v++){
                float ov = OhRow[v];
                float4 wA = *(const float4*)(Wrow + v*128);
                float4 wB = *(const float4*)(Wrow + v*128 + 4);
                acc[0]=fmaf(ov,wA.x,acc[0]); acc[1]=fmaf(ov,wA.y,acc[1]);
                acc[2]=fmaf(ov,wA.z,acc[2]); acc[3]=fmaf(ov,wA.w,acc[3]);
                acc[4]=fmaf(ov,wB.x,acc[4]); acc[5]=fmaf(ov,wB.y,acc[5]);
                acc[6]=fmaf(ov,wB.z,acc[6]); acc[7]=fmaf(ov,wB.w,acc[7]);
            }
        }
        float* op = out + (b*2048 + qt*16 + mq)*128 + e0;
        float4 oA; oA.x=acc[0]; oA.y=acc[1]; oA.z=acc[2]; oA.w=acc[3];
        float4 oB; oB.x=acc[4]; oB.y=acc[5]; oB.z=acc[6]; oB.w=acc[7];
        *(float4*)op = oA;
        *(float4*)(op+4) = oB;
    }
}

extern "C" void kernel_launch(void* const* d_in, const int* in_sizes, int n_in,
                              void* d_out, int out_size, void* d_ws, size_t ws_size,
                              hipStream_t stream) {
    const float* h    = (const float*)d_in[0];
    const float* src  = (const float*)d_in[1];
    const float* Wq   = (const float*)d_in[2];
    const float* Wk   = (const float*)d_in[3];
    const float* Wv   = (const float*)d_in[4];
    const float* Wout = (const float*)d_in[5];
    const float* w1   = (const float*)d_in[6];
    const float* b1   = (const float*)d_in[7];
    const float* w2   = (const float*)d_in[8];
    const float* b2   = (const float*)d_in[9];
    float* out = (float*)d_out;

    unsigned short* Qb = (unsigned short*)d_ws;       // 524288 bf16 = 1 MB
    unsigned short* Kb = Qb + 524288;                 // 1 MB
    unsigned short* Vt = Kb + 524288;                 // 1 MB (transposed)
    float* part = (float*)((char*)d_ws + 3*1048576);  // 17.8 MB

    qkv_kernel<<<dim3(128,12), 256, 0, stream>>>(h, Wq, Wk, Wv, Qb, Kb, Vt);
    attn_kernel<<<dim3(32,2,NSLICE), 256, 0, stream>>>(src, Qb, Kb, Vt, w1, b1, w2, b2, part, out);
    combine_kernel<<<dim3(128,2), 256, 0, stream>>>(part, Wout, out);
}